// Round 2
// baseline (539.984 us; speedup 1.0000x reference)
//
#include <hip/hip_runtime.h>
#include <hip/hip_bf16.h>

#define NEG_INF (-9999999.0f)

__device__ __forceinline__ float b2f(unsigned short u) {
  union { unsigned int i; float f; } x; x.i = ((unsigned int)u) << 16; return x.f;
}
__device__ __forceinline__ unsigned short f2b(float f) {
  union { float f; unsigned int i; } x; x.f = f;
  unsigned int r = x.i + 0x7fffu + ((x.i >> 16) & 1u);
  return (unsigned short)(r >> 16);
}
__device__ __forceinline__ float lrelu(float v) { return v > 0.f ? v : 0.01f * v; }

// out[row0+r][h] = lrelu(sum_w xs[r][w] * Wm[h][w] + bv[h]), H=W=300, ROWS rows per block
template<int ROWS>
__device__ void linear300_compute(const float (*xs)[300],
                                  const float* __restrict__ Wm,
                                  const float* __restrict__ bv,
                                  float* __restrict__ dst, int row0) {
  int t = threadIdx.x;
  for (int hb = 0; hb < 300; hb += 256) {
    int h = hb + t;
    if (h >= 300) break;
    float acc[ROWS];
    #pragma unroll
    for (int r = 0; r < ROWS; ++r) acc[r] = 0.f;
    const float* wrow = Wm + h * 300;
    for (int w = 0; w < 300; w += 4) {
      float4 wv = *reinterpret_cast<const float4*>(wrow + w);
      #pragma unroll
      for (int r = 0; r < ROWS; ++r) {
        float4 xv = *reinterpret_cast<const float4*>(&xs[r][w]);
        acc[r] = fmaf(xv.x, wv.x, acc[r]);
        acc[r] = fmaf(xv.y, wv.y, acc[r]);
        acc[r] = fmaf(xv.z, wv.z, acc[r]);
        acc[r] = fmaf(xv.w, wv.w, acc[r]);
      }
    }
    float bb = bv[h];
    #pragma unroll
    for (int r = 0; r < ROWS; ++r)
      dst[(row0 + r) * 300 + h] = lrelu(acc[r] + bb);
  }
}

// K1: gather last-word embedding rows, enc = lrelu(x @ W_sent^T + b_sent)
__global__ __launch_bounds__(256) void k_enc(const int* __restrict__ wi,
    const float* __restrict__ E,
    const float* __restrict__ Wm, const float* __restrict__ bv,
    float* __restrict__ enc) {
  __shared__ __align__(16) float xs[16][300];
  __shared__ int sidx[16];
  int t = threadIdx.x;
  int row0 = blockIdx.x * 16;
  if (t < 16) sidx[t] = wi[(row0 + t) * 64 + 63];
  __syncthreads();
  for (int n = t; n < 16 * 75; n += 256) {
    int r = n / 75, w4 = (n % 75) * 4;
    float4 ev = *reinterpret_cast<const float4*>(E + (long)sidx[r] * 300 + w4);
    *reinterpret_cast<float4*>(&xs[r][w4]) = ev;
  }
  __syncthreads();
  linear300_compute<16>(xs, Wm, bv, enc, row0);
}

// K2: P = lrelu(enc @ W_par^T + b_par); C = lrelu(enc @ W_ch^T + b_ch). 512 blocks: low half P, high half C.
__global__ __launch_bounds__(256) void k_pc(const float* __restrict__ enc,
    const float* __restrict__ Wp, const float* __restrict__ bp,
    const float* __restrict__ Wc, const float* __restrict__ bc,
    float* __restrict__ P, float* __restrict__ C) {
  __shared__ __align__(16) float xs[16][300];
  int t = threadIdx.x;
  int which = blockIdx.x >> 8;
  int row0 = (blockIdx.x & 255) * 16;
  const float4* src = reinterpret_cast<const float4*>(enc + row0 * 300);
  float4* xf = reinterpret_cast<float4*>(&xs[0][0]);
  for (int n = t; n < 1200; n += 256) xf[n] = src[n];
  __syncthreads();
  if (which == 0) linear300_compute<16>(xs, Wp, bp, P, row0);
  else            linear300_compute<16>(xs, Wc, bc, C, row0);
}

// K3: scores = enc @ w_root + b_root; fri = softmax over S per doc (written straight to d_out region)
__global__ __launch_bounds__(64) void k_fri(const float* __restrict__ enc,
    const float* __restrict__ w_root, const float* __restrict__ b_root,
    float* __restrict__ outF) {
  __shared__ float wr[300];
  int d = blockIdx.x, i = threadIdx.x;
  for (int h = i; h < 300; h += 64) wr[h] = w_root[h];
  __syncthreads();
  const float* er = enc + (d * 64 + i) * 300;
  float s = 0.f;
  for (int h = 0; h < 300; ++h) s = fmaf(er[h], wr[h], s);
  s += b_root[0];
  float m = s;
  #pragma unroll
  for (int o = 32; o > 0; o >>= 1) m = fmaxf(m, __shfl_xor(m, o, 64));
  float e = expf(s - m);
  float sum = e;
  #pragma unroll
  for (int o = 32; o > 0; o >>= 1) sum += __shfl_xor(sum, o, 64);
  outF[d * 64 + i] = e / sum;
}

// K4: per doc: A = P C^T, diag=NEG, softmax over axis 1 (over i, per column j); write to d_out region
__global__ __launch_bounds__(256) void k_attn(const float* __restrict__ P,
    const float* __restrict__ C, float* __restrict__ Aout) {
  __shared__ unsigned short Ps[64 * 300];
  __shared__ unsigned short Cs[32 * 300];
  int d = blockIdx.x, t = threadIdx.x;
  const float* Pd = P + (long)d * 19200;
  const float* Cd = C + (long)d * 19200;
  for (int n = t; n < 19200; n += 256) Ps[n] = f2b(Pd[n]);
  int jl = t >> 3, q = t & 7;   // thread -> (column j, i-range q)
  int i0 = q * 8;
  long base = (long)d * 4096;
  for (int jt = 0; jt < 2; ++jt) {
    __syncthreads();
    for (int n = t; n < 9600; n += 256) Cs[n] = f2b(Cd[jt * 9600 + n]);
    __syncthreads();
    int j = jt * 32 + jl;
    float a[8];
    #pragma unroll
    for (int k = 0; k < 8; ++k) a[k] = 0.f;
    for (int w = 0; w < 300; w += 4) {
      ushort4 cu = *reinterpret_cast<const ushort4*>(Cs + jl * 300 + w);
      float c0 = b2f(cu.x), c1 = b2f(cu.y), c2 = b2f(cu.z), c3 = b2f(cu.w);
      #pragma unroll
      for (int k = 0; k < 8; ++k) {
        ushort4 pu = *reinterpret_cast<const ushort4*>(Ps + (i0 + k) * 300 + w);
        a[k] = fmaf(b2f(pu.x), c0, a[k]);
        a[k] = fmaf(b2f(pu.y), c1, a[k]);
        a[k] = fmaf(b2f(pu.z), c2, a[k]);
        a[k] = fmaf(b2f(pu.w), c3, a[k]);
      }
    }
    #pragma unroll
    for (int k = 0; k < 8; ++k) if (i0 + k == j) a[k] = NEG_INF;
    // softmax over i: local max over 8 regs, then across the 8 lanes sharing j
    float m = a[0];
    #pragma unroll
    for (int k = 1; k < 8; ++k) m = fmaxf(m, a[k]);
    #pragma unroll
    for (int o = 1; o < 8; o <<= 1) m = fmaxf(m, __shfl_xor(m, o, 8));
    float ev[8], sum = 0.f;
    #pragma unroll
    for (int k = 0; k < 8; ++k) { ev[k] = expf(a[k] - m); sum += ev[k]; }
    #pragma unroll
    for (int o = 1; o < 8; o <<= 1) sum += __shfl_xor(sum, o, 8);
    float inv = 1.f / sum;
    #pragma unroll
    for (int k = 0; k < 8; ++k)
      Aout[base + (i0 + k) * 64 + j] = ev[k] * inv;
  }
}

// K5: per 16 rows (within one doc): rowsum, colA, u=[enc | A^T enc + fri*root | enc*rowsum], ri = lrelu(u @ W_r^T + b_r)
__global__ __launch_bounds__(256) void k_ri(const float* __restrict__ Aw,
    const float* __restrict__ friw, const float* __restrict__ enc,
    const float* __restrict__ root_embed,
    const float* __restrict__ W_r, const float* __restrict__ b_r,
    float* __restrict__ ri) {
  __shared__ __align__(16) float u[16][900];
  __shared__ float colA[16][64];
  __shared__ float rowsumS[16];
  __shared__ float friS[16];
  int t = threadIdx.x;
  int row0 = blockIdx.x * 16;
  int d = row0 >> 6;
  int i0 = row0 & 63;
  int r = t >> 4, c = t & 15;
  long Abase = (long)d * 4096;
  // rowsum over j for my 16 rows (16 threads/row, 4 j each)
  const float* Arow = Aw + Abase + (i0 + r) * 64 + c * 4;
  float p = Arow[0] + Arow[1] + Arow[2] + Arow[3];
  #pragma unroll
  for (int o = 1; o < 16; o <<= 1) p += __shfl_xor(p, o, 16);
  if (c == 0) { rowsumS[r] = p; friS[r] = friw[d * 64 + i0 + r]; }
  // column of A: colA[r][k] = A[d][k][i0+r]
  #pragma unroll
  for (int kk = 0; kk < 4; ++kk) {
    int k = c * 4 + kk;
    colA[r][k] = Aw[Abase + k * 64 + i0 + r];
  }
  __syncthreads();
  for (int hb = 0; hb < 300; hb += 256) {
    int h = hb + t;
    if (h >= 300) break;
    float racc[16];
    #pragma unroll
    for (int r2 = 0; r2 < 16; ++r2) racc[r2] = 0.f;
    for (int k = 0; k < 64; ++k) {
      float e = enc[(d * 64 + k) * 300 + h];
      #pragma unroll
      for (int r2 = 0; r2 < 16; ++r2) racc[r2] = fmaf(colA[r2][k], e, racc[r2]);
    }
    float re = root_embed[h];
    #pragma unroll
    for (int r2 = 0; r2 < 16; ++r2) {
      u[r2][300 + h] = racc[r2] + friS[r2] * re;
      float e2 = enc[(row0 + r2) * 300 + h];
      u[r2][h] = e2;
      u[r2][600 + h] = e2 * rowsumS[r2];
    }
  }
  __syncthreads();
  for (int hb = 0; hb < 300; hb += 256) {
    int h = hb + t;
    if (h >= 300) break;
    float acc[16];
    #pragma unroll
    for (int r2 = 0; r2 < 16; ++r2) acc[r2] = 0.f;
    const float* wrow = W_r + h * 900;
    for (int cc = 0; cc < 900; cc += 4) {
      float4 wv = *reinterpret_cast<const float4*>(wrow + cc);
      #pragma unroll
      for (int r2 = 0; r2 < 16; ++r2) {
        float4 uv = *reinterpret_cast<const float4*>(&u[r2][cc]);
        acc[r2] = fmaf(uv.x, wv.x, acc[r2]);
        acc[r2] = fmaf(uv.y, wv.y, acc[r2]);
        acc[r2] = fmaf(uv.z, wv.z, acc[r2]);
        acc[r2] = fmaf(uv.w, wv.w, acc[r2]);
      }
    }
    float bb = b_r[h];
    #pragma unroll
    for (int r2 = 0; r2 < 16; ++r2)
      ri[(row0 + r2) * 300 + h] = lrelu(acc[r2] + bb);
  }
}

// K6: final = mean_i ri; out = final @ W_cls^T + b_cls
__global__ __launch_bounds__(256) void k_final(const float* __restrict__ ri,
    const float* __restrict__ W_cls, const float* __restrict__ b_cls,
    float* __restrict__ outp) {
  __shared__ float fin[300];
  __shared__ float red[256];
  int d = blockIdx.x, t = threadIdx.x;
  for (int h = t; h < 300; h += 256) {
    float s = 0.f;
    for (int i = 0; i < 64; ++i) s += ri[((d * 64) + i) * 300 + h];
    fin[h] = s * (1.0f / 64.0f);
  }
  __syncthreads();
  for (int c2 = 0; c2 < 2; ++c2) {
    float pth = 0.f;
    for (int h = t; h < 300; h += 256) pth = fmaf(fin[h], W_cls[c2 * 300 + h], pth);
    red[t] = pth;
    __syncthreads();
    for (int o = 128; o > 0; o >>= 1) {
      if (t < o) red[t] += red[t + o];
      __syncthreads();
    }
    if (t == 0) outp[d * 2 + c2] = red[0] + b_cls[c2];
    __syncthreads();
  }
}

extern "C" void kernel_launch(void* const* d_in, const int* in_sizes, int n_in,
                              void* d_out, int out_size, void* d_ws, size_t ws_size,
                              hipStream_t stream) {
  const int*   wi     = (const int*)d_in[0];
  const float* E      = (const float*)d_in[1];
  const float* W_sent = (const float*)d_in[2];
  const float* b_sent = (const float*)d_in[3];
  const float* W_par  = (const float*)d_in[4];
  const float* b_par  = (const float*)d_in[5];
  const float* W_ch   = (const float*)d_in[6];
  const float* b_ch   = (const float*)d_in[7];
  const float* w_root = (const float*)d_in[8];
  const float* b_root = (const float*)d_in[9];
  const float* root_e = (const float*)d_in[10];
  const float* W_r    = (const float*)d_in[11];
  const float* b_r    = (const float*)d_in[12];
  const float* W_cls  = (const float*)d_in[13];
  const float* b_cls  = (const float*)d_in[14];

  float* ws   = (float*)d_ws;
  float* enc  = ws;                 // 4096*300 = 1228800
  float* P    = ws + 1228800;       // 1228800
  float* C    = ws + 2457600;       // 1228800
  float* ri   = ws + 3686400;       // 1228800

  float* outp = (float*)d_out;      // [out(128) | A(262144) | fri(4096)]
  float* outA = outp + 128;
  float* outF = outp + 128 + 262144;

  k_enc  <<<256, 256, 0, stream>>>(wi, E, W_sent, b_sent, enc);
  k_pc   <<<512, 256, 0, stream>>>(enc, W_par, b_par, W_ch, b_ch, P, C);
  k_fri  <<<64,  64,  0, stream>>>(enc, w_root, b_root, outF);
  k_attn <<<64,  256, 0, stream>>>(P, C, outA);
  k_ri   <<<256, 256, 0, stream>>>(outA, outF, enc, root_e, W_r, b_r, ri);
  k_final<<<64,  256, 0, stream>>>(ri, W_cls, b_cls, outp);
}

// Round 3
// 266.363 us; speedup vs baseline: 2.0272x; 2.0272x over previous
//
#include <hip/hip_runtime.h>
#include <hip/hip_bf16.h>

#define NEG_INF (-9999999.0f)

typedef __attribute__((ext_vector_type(8))) short bf16x8;
typedef __attribute__((ext_vector_type(4))) float f32x4;
typedef unsigned short us;

__device__ __forceinline__ float b2f(us u) {
  union { unsigned int i; float f; } x; x.i = ((unsigned int)u) << 16; return x.f;
}
__device__ __forceinline__ us f2b(float f) {
  union { float f; unsigned int i; } x; x.f = f;
  unsigned int r = x.i + 0x7fffu + ((x.i >> 16) & 1u);
  return (us)(r >> 16);
}
__device__ __forceinline__ float lrelu(float v) { return v > 0.f ? v : 0.01f * v; }
__device__ __forceinline__ bf16x8 ld8(const us* p) { return *reinterpret_cast<const bf16x8*>(p); }

// ---------------- prep: convert weights + gathered embeddings to padded bf16 ----------------
// task (blockIdx.y): 0..2 W_{sent,par,ch} -> [304][320]; 3: W_r -> [304][928];
// 4: xg[4096][320] = gathered E rows; 5: zero pad cols [300,320) of enc_b/P_b/C_b.
__global__ __launch_bounds__(256) void k_prep(const int* __restrict__ wi, const float* __restrict__ E,
    const float* __restrict__ Ws, const float* __restrict__ Wp, const float* __restrict__ Wc,
    const float* __restrict__ Wr,
    us* __restrict__ Wsb, us* __restrict__ Wpb, us* __restrict__ Wcb, us* __restrict__ Wrb,
    us* __restrict__ xg, us* __restrict__ encb, us* __restrict__ Pb, us* __restrict__ Cb) {
  int task = blockIdx.y;
  int gid = blockIdx.x * 256 + threadIdx.x;
  const int stride = 640 * 256;
  if (task < 3) {
    const float* src = (task == 0) ? Ws : (task == 1) ? Wp : Wc;
    us* dst = (task == 0) ? Wsb : (task == 1) ? Wpb : Wcb;
    for (int i = gid; i < 304 * 320; i += stride) {
      int r = i / 320, c = i - r * 320;
      dst[i] = (r < 300 && c < 300) ? f2b(src[r * 300 + c]) : 0;
    }
  } else if (task == 3) {
    for (int i = gid; i < 304 * 928; i += stride) {
      int r = i / 928, c = i - r * 928;
      Wrb[i] = (r < 300 && c < 900) ? f2b(Wr[r * 900 + c]) : 0;
    }
  } else if (task == 4) {
    for (int i = gid; i < 4096 * 320; i += stride) {
      int r = i / 320, c = i - r * 320;
      xg[i] = (c < 300) ? f2b(E[(long)wi[r * 64 + 63] * 300 + c]) : 0;
    }
  } else {
    for (int i = gid; i < 3 * 4096 * 20; i += stride) {
      int b = i / 81920, rem = i - b * 81920;
      int r = rem / 20, c = 300 + (rem - r * 20);
      us* dst = (b == 0) ? encb : (b == 1) ? Pb : Cb;
      dst[r * 320 + c] = 0;
    }
  }
}

// ---------------- generic MFMA GEMM: C[M=4096][300] = lrelu(A(bf16,[M][Kp]) . B(bf16,[304][Kp])^T + bias)
// grid = 64 m-blocks x 5 n-groups (4 n-tiles each, last 3). 4 waves/block, wave = one 16-row m-tile.
// mode 0: bf16 out; mode 1: bf16 out + bf16 transposed out; mode 2: fp32 out.
__global__ __launch_bounds__(256) void k_gemm(
    const us* __restrict__ Ab, int apitch,
    const us* __restrict__ Bb, int bpitch, int ksteps,
    const float* __restrict__ bias,
    us* __restrict__ outb, int opitch,
    us* __restrict__ outT, int tpitch,
    float* __restrict__ outf, int fpitch, int mode) {
  int bid = blockIdx.x;
  int mb = bid & 63, ng = bid >> 6;
  int w = threadIdx.x >> 6, lane = threadIdx.x & 63;
  int lo = lane & 15, q = lane >> 4;
  int m0 = mb * 64 + w * 16;
  int nt0 = ng * 4;
  int ntc = 19 - nt0; if (ntc > 4) ntc = 4;

  f32x4 z = {0.f, 0.f, 0.f, 0.f};
  f32x4 acc[4]; acc[0] = z; acc[1] = z; acc[2] = z; acc[3] = z;

  const us* arow = Ab + (long)(m0 + lo) * apitch + 8 * q;
  const us* brow[4];
  #pragma unroll
  for (int t2 = 0; t2 < 4; ++t2)
    brow[t2] = Bb + (long)((nt0 + t2) * 16 + lo) * bpitch + 8 * q;

  for (int ks = 0; ks < ksteps; ++ks) {
    bf16x8 av = ld8(arow + ks * 32);
    #pragma unroll
    for (int t2 = 0; t2 < 4; ++t2) {
      if (t2 < ntc) {
        bf16x8 bv = ld8(brow[t2] + ks * 32);
        acc[t2] = __builtin_amdgcn_mfma_f32_16x16x32_bf16(av, bv, acc[t2], 0, 0, 0);
      }
    }
  }
  #pragma unroll
  for (int t2 = 0; t2 < 4; ++t2) {
    if (t2 >= ntc) continue;
    int col = (nt0 + t2) * 16 + lo;
    if (col >= 300) continue;
    float bb = bias[col];
    #pragma unroll
    for (int r = 0; r < 4; ++r) {
      int row = m0 + q * 4 + r;
      float v = lrelu(acc[t2][r] + bb);
      if (mode == 2) {
        outf[(long)row * fpitch + col] = v;
      } else {
        us h = f2b(v);
        outb[(long)row * opitch + col] = h;
        if (mode == 1) outT[(long)col * tpitch + row] = h;
      }
    }
  }
}

// ---------------- fri: scores = enc . w_root + b_root, softmax over S ----------------
__global__ __launch_bounds__(64) void k_fri(const us* __restrict__ encb,
    const float* __restrict__ w_root, const float* __restrict__ b_root,
    float* __restrict__ outF) {
  __shared__ float wr[300];
  int d = blockIdx.x, i = threadIdx.x;
  for (int h = i; h < 300; h += 64) wr[h] = w_root[h];
  __syncthreads();
  const us* er = encb + (long)(d * 64 + i) * 320;
  float s = 0.f;
  for (int h = 0; h < 300; h += 4) {
    ushort4 e4 = *reinterpret_cast<const ushort4*>(er + h);
    s = fmaf(b2f(e4.x), wr[h], s);
    s = fmaf(b2f(e4.y), wr[h + 1], s);
    s = fmaf(b2f(e4.z), wr[h + 2], s);
    s = fmaf(b2f(e4.w), wr[h + 3], s);
  }
  s += b_root[0];
  float m = s;
  #pragma unroll
  for (int o = 32; o > 0; o >>= 1) m = fmaxf(m, __shfl_xor(m, o, 64));
  float e = expf(s - m);
  float sum = e;
  #pragma unroll
  for (int o = 32; o > 0; o >>= 1) sum += __shfl_xor(sum, o, 64);
  outF[d * 64 + i] = e / sum;
}

// ---------------- attn: per doc, logits = P.C^T (MFMA), diag=NEG, softmax over i per column j ----------------
__global__ __launch_bounds__(256) void k_attn(const us* __restrict__ Pb, const us* __restrict__ Cb,
    float* __restrict__ Aout, us* __restrict__ Atb) {
  __shared__ float Ls[64][65];
  __shared__ float pm[4][64], psum[4][64];
  int d = blockIdx.x;
  int w = threadIdx.x >> 6, lane = threadIdx.x & 63;
  int lo = lane & 15, q = lane >> 4;
  const us* Pd = Pb + (long)d * 64 * 320;
  const us* Cd = Cb + (long)d * 64 * 320;
  f32x4 z = {0.f, 0.f, 0.f, 0.f};
  f32x4 acc[4]; acc[0] = z; acc[1] = z; acc[2] = z; acc[3] = z;
  const us* arow = Pd + (w * 16 + lo) * 320 + 8 * q;
  for (int ks = 0; ks < 10; ++ks) {
    bf16x8 av = ld8(arow + ks * 32);
    #pragma unroll
    for (int t2 = 0; t2 < 4; ++t2) {
      bf16x8 bv = ld8(Cd + (t2 * 16 + lo) * 320 + ks * 32 + 8 * q);
      acc[t2] = __builtin_amdgcn_mfma_f32_16x16x32_bf16(av, bv, acc[t2], 0, 0, 0);
    }
  }
  #pragma unroll
  for (int t2 = 0; t2 < 4; ++t2) {
    #pragma unroll
    for (int r = 0; r < 4; ++r) {
      int i = w * 16 + q * 4 + r, j = t2 * 16 + lo;
      Ls[i][j] = (i == j) ? NEG_INF : acc[t2][r];
    }
  }
  __syncthreads();
  int j = threadIdx.x & 63, p = threadIdx.x >> 6;
  float mx = -3.0e38f;
  for (int i = p * 16; i < p * 16 + 16; ++i) mx = fmaxf(mx, Ls[i][j]);
  pm[p][j] = mx;
  __syncthreads();
  float gmx = fmaxf(fmaxf(pm[0][j], pm[1][j]), fmaxf(pm[2][j], pm[3][j]));
  float s = 0.f;
  for (int i = p * 16; i < p * 16 + 16; ++i) s += expf(Ls[i][j] - gmx);
  psum[p][j] = s;
  __syncthreads();
  float inv = 1.f / (psum[0][j] + psum[1][j] + psum[2][j] + psum[3][j]);
  float* Ad = Aout + (long)d * 4096;
  us* Atd = Atb + (long)d * 4096;
  for (int i = p * 16; i < p * 16 + 16; ++i) {
    float a = expf(Ls[i][j] - gmx) * inv;
    Ad[i * 64 + j] = a;
    Atd[j * 64 + i] = f2b(a);
  }
}

// ---------------- glue: per doc, tmp = A^T.enc via MFMA, build u = [enc | tmp+fri*root | enc*rowsum] (bf16) ----------------
__global__ __launch_bounds__(256) void k_glue(const float* __restrict__ Aout, const float* __restrict__ fri,
    const us* __restrict__ encb, const us* __restrict__ encTb, const us* __restrict__ Atb,
    const float* __restrict__ root, us* __restrict__ ub) {
  __shared__ float rs[64], frs[64];
  int d = blockIdx.x, t = threadIdx.x;
  const float* Ad = Aout + (long)d * 4096;
  if (t < 64) {
    float s = 0.f;
    for (int j2 = 0; j2 < 64; j2 += 4) {
      float4 v = *reinterpret_cast<const float4*>(Ad + t * 64 + j2);
      s += v.x + v.y + v.z + v.w;
    }
    rs[t] = s;
    frs[t] = fri[d * 64 + t];
  }
  __syncthreads();
  int w = t >> 6, lane = t & 63, lo = lane & 15, q = lane >> 4;
  const us* Atd = Atb + (long)d * 4096;
  bf16x8 av0 = ld8(Atd + (w * 16 + lo) * 64 + 8 * q);
  bf16x8 av1 = ld8(Atd + (w * 16 + lo) * 64 + 32 + 8 * q);
  for (int nt = 0; nt < 19; ++nt) {
    f32x4 acc = {0.f, 0.f, 0.f, 0.f};
    const us* brow = encTb + (long)(nt * 16 + lo) * 4096 + d * 64 + 8 * q;
    bf16x8 bv0 = ld8(brow);
    bf16x8 bv1 = ld8(brow + 32);
    acc = __builtin_amdgcn_mfma_f32_16x16x32_bf16(av0, bv0, acc, 0, 0, 0);
    acc = __builtin_amdgcn_mfma_f32_16x16x32_bf16(av1, bv1, acc, 0, 0, 0);
    int h = nt * 16 + lo;
    if (h < 300) {
      float rt = root[h];
      #pragma unroll
      for (int r = 0; r < 4; ++r) {
        int i = w * 16 + q * 4 + r;
        ub[(long)(d * 64 + i) * 928 + 300 + h] = f2b(acc[r] + frs[i] * rt);
      }
    }
  }
  // seg0 copy, seg2 scale, zero K-pad cols [900,928)
  for (int idx = t; idx < 64 * 300; idx += 256) {
    int r = idx / 300, c = idx - r * 300;
    us ev = encb[(long)(d * 64 + r) * 320 + c];
    ub[(long)(d * 64 + r) * 928 + c] = ev;
    ub[(long)(d * 64 + r) * 928 + 600 + c] = f2b(b2f(ev) * rs[r]);
  }
  for (int idx = t; idx < 64 * 28; idx += 256) {
    int r = idx / 28, c = 900 + (idx - r * 28);
    ub[(long)(d * 64 + r) * 928 + c] = 0;
  }
}

// ---------------- final: mean over i, tiny head ----------------
__global__ __launch_bounds__(256) void k_final(const float* __restrict__ ri,
    const float* __restrict__ W_cls, const float* __restrict__ b_cls,
    float* __restrict__ outp) {
  __shared__ float fin[300];
  __shared__ float red[256];
  int d = blockIdx.x, t = threadIdx.x;
  for (int h = t; h < 300; h += 256) {
    float s = 0.f;
    for (int i = 0; i < 64; ++i) s += ri[((d * 64) + i) * 300 + h];
    fin[h] = s * (1.0f / 64.0f);
  }
  __syncthreads();
  for (int c2 = 0; c2 < 2; ++c2) {
    float pth = 0.f;
    for (int h = t; h < 300; h += 256) pth = fmaf(fin[h], W_cls[c2 * 300 + h], pth);
    red[t] = pth;
    __syncthreads();
    for (int o = 128; o > 0; o >>= 1) {
      if (t < o) red[t] += red[t + o];
      __syncthreads();
    }
    if (t == 0) outp[d * 2 + c2] = red[0] + b_cls[c2];
    __syncthreads();
  }
}

extern "C" void kernel_launch(void* const* d_in, const int* in_sizes, int n_in,
                              void* d_out, int out_size, void* d_ws, size_t ws_size,
                              hipStream_t stream) {
  const int*   wi     = (const int*)d_in[0];
  const float* E      = (const float*)d_in[1];
  const float* W_sent = (const float*)d_in[2];
  const float* b_sent = (const float*)d_in[3];
  const float* W_par  = (const float*)d_in[4];
  const float* b_par  = (const float*)d_in[5];
  const float* W_ch   = (const float*)d_in[6];
  const float* b_ch   = (const float*)d_in[7];
  const float* w_root = (const float*)d_in[8];
  const float* b_root = (const float*)d_in[9];
  const float* root_e = (const float*)d_in[10];
  const float* W_r    = (const float*)d_in[11];
  const float* b_r    = (const float*)d_in[12];
  const float* W_cls  = (const float*)d_in[13];
  const float* b_cls  = (const float*)d_in[14];

  us* B = (us*)d_ws;
  us* Wsb  = B;                  //  97,280  [304][320]
  us* Wpb  = B + 97280;          //  97,280
  us* Wcb  = B + 194560;         //  97,280
  us* Wrb  = B + 291840;         // 282,112  [304][928]
  us* R    = B + 573952;         // region, 3,932,160 us
  us* xg   = R;                  // [4096][320]   (dead after k_enc)
  us* Pb   = R + 1310720;        // [4096][320]   (dead after k_attn)
  us* Cb   = R + 2621440;        // [4096][320]   (dead after k_attn)
  us* ub   = R;                  // [4096][928]  aliases xg/Pb/Cb (written in k_glue, after attn)
  us* encb = B + 4506112;        // [4096][320]
  us* encTb= B + 5816832;        // [304][4096]
  us* Atb  = B + 7062016;        // [64][64][64] (A transposed per doc, bf16)
  float* ri = (float*)(B + 7324160);  // [4096][300] fp32

  float* outp = (float*)d_out;      // [out(128) | A(262144) | fri(4096)]
  float* outA = outp + 128;
  float* outF = outp + 128 + 262144;

  k_prep<<<dim3(640, 6), 256, 0, stream>>>(wi, E, W_sent, W_par, W_ch, W_r,
                                           Wsb, Wpb, Wcb, Wrb, xg, encb, Pb, Cb);
  // enc = lrelu(xg . Wsent^T + b_sent), also emit enc^T
  k_gemm<<<320, 256, 0, stream>>>(xg, 320, Wsb, 320, 10, b_sent,
                                  encb, 320, encTb, 4096, (float*)nullptr, 0, 1);
  k_fri<<<64, 64, 0, stream>>>(encb, w_root, b_root, outF);
  k_gemm<<<320, 256, 0, stream>>>(encb, 320, Wpb, 320, 10, b_par,
                                  Pb, 320, (us*)nullptr, 0, (float*)nullptr, 0, 0);
  k_gemm<<<320, 256, 0, stream>>>(encb, 320, Wcb, 320, 10, b_ch,
                                  Cb, 320, (us*)nullptr, 0, (float*)nullptr, 0, 0);
  k_attn<<<64, 256, 0, stream>>>(Pb, Cb, outA, Atb);
  k_glue<<<64, 256, 0, stream>>>(outA, outF, encb, encTb, Atb, root_e, ub);
  // ri = lrelu(u . W_r^T + b_r), fp32 out
  k_gemm<<<320, 256, 0, stream>>>(ub, 928, Wrb, 928, 29, b_r,
                                  (us*)nullptr, 0, (us*)nullptr, 0, ri, 300, 2);
  k_final<<<64, 256, 0, stream>>>(ri, W_cls, b_cls, outp);
}

// Round 4
// 224.029 us; speedup vs baseline: 2.4103x; 1.1890x over previous
//
#include <hip/hip_runtime.h>
#include <hip/hip_bf16.h>

#define NEG_INF (-9999999.0f)

typedef __attribute__((ext_vector_type(8))) short bf16x8;
typedef __attribute__((ext_vector_type(4))) float f32x4;
typedef unsigned short us;

__device__ __forceinline__ float b2f(us u) {
  union { unsigned int i; float f; } x; x.i = ((unsigned int)u) << 16; return x.f;
}
__device__ __forceinline__ us f2b(float f) {
  union { float f; unsigned int i; } x; x.f = f;
  unsigned int r = x.i + 0x7fffu + ((x.i >> 16) & 1u);
  return (us)(r >> 16);
}
__device__ __forceinline__ float lrelu(float v) { return v > 0.f ? v : 0.01f * v; }
__device__ __forceinline__ bf16x8 ld8(const us* p) { return *reinterpret_cast<const bf16x8*>(p); }

// ---------------- prep: convert weights + gathered embeddings to padded bf16 ----------------
__global__ __launch_bounds__(256) void k_prep(const int* __restrict__ wi, const float* __restrict__ E,
    const float* __restrict__ Ws, const float* __restrict__ Wp, const float* __restrict__ Wc,
    const float* __restrict__ Wr,
    us* __restrict__ Wsb, us* __restrict__ Wpb, us* __restrict__ Wcb, us* __restrict__ Wrb,
    us* __restrict__ xg, us* __restrict__ encb, us* __restrict__ Pb, us* __restrict__ Cb) {
  int task = blockIdx.y;
  int gid = blockIdx.x * 256 + threadIdx.x;
  const int stride = 640 * 256;
  if (task < 3) {
    const float* src = (task == 0) ? Ws : (task == 1) ? Wp : Wc;
    us* dst = (task == 0) ? Wsb : (task == 1) ? Wpb : Wcb;
    for (int i = gid; i < 304 * 320; i += stride) {
      int r = i / 320, c = i - r * 320;
      dst[i] = (r < 300 && c < 300) ? f2b(src[r * 300 + c]) : 0;
    }
  } else if (task == 3) {
    for (int i = gid; i < 304 * 928; i += stride) {
      int r = i / 928, c = i - r * 928;
      Wrb[i] = (r < 300 && c < 900) ? f2b(Wr[r * 900 + c]) : 0;
    }
  } else if (task == 4) {
    for (int i = gid; i < 4096 * 320; i += stride) {
      int r = i / 320, c = i - r * 320;
      xg[i] = (c < 300) ? f2b(E[(long)wi[r * 64 + 63] * 300 + c]) : 0;
    }
  } else {
    for (int i = gid; i < 3 * 4096 * 20; i += stride) {
      int b = i / 81920, rem = i - b * 81920;
      int r = rem / 20, c = 300 + (rem - r * 20);
      us* dst = (b == 0) ? encb : (b == 1) ? Pb : Cb;
      dst[r * 320 + c] = 0;
    }
  }
}

// ---------------- MFMA sweep: one wave, 16 m-rows x NT n-tiles, register double-buffered ----------------
template<int NT>
__device__ __forceinline__ void sweep(const us* __restrict__ Ab, int apitch,
    const us* __restrict__ Bb, int bpitch, int m0, int nt0, int lo, int q,
    int ks0, int ksn, f32x4* acc) {
  const us* ar = Ab + (long)(m0 + lo) * apitch + 8 * q + (long)ks0 * 32;
  const us* br[NT];
#pragma unroll
  for (int t = 0; t < NT; ++t)
    br[t] = Bb + (long)((nt0 + t) * 16 + lo) * bpitch + 8 * q + (long)ks0 * 32;
  bf16x8 ac = ld8(ar);
  bf16x8 bc[NT];
#pragma unroll
  for (int t = 0; t < NT; ++t) bc[t] = ld8(br[t]);
  for (int ks = 0; ks < ksn - 1; ++ks) {
    bf16x8 an = ld8(ar + (ks + 1) * 32);
    bf16x8 bn[NT];
#pragma unroll
    for (int t = 0; t < NT; ++t) bn[t] = ld8(br[t] + (ks + 1) * 32);
#pragma unroll
    for (int t = 0; t < NT; ++t)
      acc[t] = __builtin_amdgcn_mfma_f32_16x16x32_bf16(ac, bc[t], acc[t], 0, 0, 0);
    ac = an;
#pragma unroll
    for (int t = 0; t < NT; ++t) bc[t] = bn[t];
  }
#pragma unroll
  for (int t = 0; t < NT; ++t)
    acc[t] = __builtin_amdgcn_mfma_f32_16x16x32_bf16(ac, bc[t], acc[t], 0, 0, 0);
}

template<int NT>
__device__ __forceinline__ void epi_bf16(const f32x4* acc, const float* __restrict__ bias,
    us* __restrict__ outb, int opitch, us* __restrict__ outT, int tpitch,
    int m0, int nt0, int lo, int q) {
#pragma unroll
  for (int t = 0; t < NT; ++t) {
    int col = (nt0 + t) * 16 + lo;
    if (col >= 300) continue;
    float bb = bias[col];
#pragma unroll
    for (int r = 0; r < 4; ++r) {
      int row = m0 + q * 4 + r;
      us h = f2b(lrelu(acc[t][r] + bb));
      outb[(long)row * opitch + col] = h;
      if (outT) outT[(long)col * tpitch + row] = h;
    }
  }
}

template<int NT>
__device__ __forceinline__ void epi_f32(const f32x4* acc, float* __restrict__ pf,
    int m0, int nt0, int lo, int q) {
#pragma unroll
  for (int t = 0; t < NT; ++t) {
    int col = (nt0 + t) * 16 + lo;
    if (col >= 300) continue;
#pragma unroll
    for (int r = 0; r < 4; ++r)
      pf[(long)(m0 + q * 4 + r) * 300 + col] = acc[t][r];
  }
}

// ---------------- bf16-out GEMM (K=320): grid.x = m-tile, grid.y selects (B,bias,out) set ----------------
__global__ __launch_bounds__(256) void k_gemm_b(const us* __restrict__ Ab,
    const us* __restrict__ B0, const float* __restrict__ bias0, us* __restrict__ out0,
    const us* __restrict__ B1, const float* __restrict__ bias1, us* __restrict__ out1,
    us* __restrict__ outT) {
  const us* Bb = blockIdx.y ? B1 : B0;
  const float* bias = blockIdx.y ? bias1 : bias0;
  us* outb = blockIdx.y ? out1 : out0;
  us* oT = blockIdx.y ? (us*)nullptr : outT;
  int w = threadIdx.x >> 6, lane = threadIdx.x & 63;
  int lo = lane & 15, q = lane >> 4;
  int m0 = blockIdx.x * 16;
  f32x4 z = {0.f, 0.f, 0.f, 0.f};
  if (w < 3) {
    f32x4 acc[5] = {z, z, z, z, z};
    sweep<5>(Ab, 320, Bb, 320, m0, w * 5, lo, q, 0, 10, acc);
    epi_bf16<5>(acc, bias, outb, 320, oT, 4096, m0, w * 5, lo, q);
  } else {
    f32x4 acc[4] = {z, z, z, z};
    sweep<4>(Ab, 320, Bb, 320, m0, 15, lo, q, 0, 10, acc);
    epi_bf16<4>(acc, bias, outb, 320, oT, 4096, m0, 15, lo, q);
  }
}

// ---------------- ri GEMM (K=928, split in 2 halves over grid.y), fp32 partial out ----------------
__global__ __launch_bounds__(256) void k_gemm_ri(const us* __restrict__ Ab,
    const us* __restrict__ Bb, float* __restrict__ p0, float* __restrict__ p1) {
  int w = threadIdx.x >> 6, lane = threadIdx.x & 63;
  int lo = lane & 15, q = lane >> 4;
  int m0 = blockIdx.x * 16;
  int y = blockIdx.y;
  int ks0 = y ? 15 : 0, ksn = y ? 14 : 15;
  float* pf = y ? p1 : p0;
  f32x4 z = {0.f, 0.f, 0.f, 0.f};
  if (w < 3) {
    f32x4 acc[5] = {z, z, z, z, z};
    sweep<5>(Ab, 928, Bb, 928, m0, w * 5, lo, q, ks0, ksn, acc);
    epi_f32<5>(acc, pf, m0, w * 5, lo, q);
  } else {
    f32x4 acc[4] = {z, z, z, z};
    sweep<4>(Ab, 928, Bb, 928, m0, 15, lo, q, ks0, ksn, acc);
    epi_f32<4>(acc, pf, m0, 15, lo, q);
  }
}

// ---------------- finish ri: ri = lrelu(p0 + p1 + bias), in place over p1 ----------------
__global__ __launch_bounds__(256) void k_finish(const float* __restrict__ p0,
    const float* __restrict__ p1, const float* __restrict__ bias, float* __restrict__ ri) {
  int r0 = blockIdx.x * 2;
  for (int n = threadIdx.x; n < 600; n += 256) {
    int hi = (n >= 300) ? 1 : 0;
    int row = r0 + hi, col = n - hi * 300;
    long i = (long)row * 300 + col;
    ri[i] = lrelu(p0[i] + p1[i] + bias[col]);
  }
}

// ---------------- fri: scores = enc . w_root + b_root, softmax over S ----------------
__global__ __launch_bounds__(64) void k_fri(const us* __restrict__ encb,
    const float* __restrict__ w_root, const float* __restrict__ b_root,
    float* __restrict__ outF) {
  __shared__ float wr[300];
  int d = blockIdx.x, i = threadIdx.x;
  for (int h = i; h < 300; h += 64) wr[h] = w_root[h];
  __syncthreads();
  const us* er = encb + (long)(d * 64 + i) * 320;
  float s = 0.f;
  for (int h = 0; h < 300; h += 4) {
    ushort4 e4 = *reinterpret_cast<const ushort4*>(er + h);
    s = fmaf(b2f(e4.x), wr[h], s);
    s = fmaf(b2f(e4.y), wr[h + 1], s);
    s = fmaf(b2f(e4.z), wr[h + 2], s);
    s = fmaf(b2f(e4.w), wr[h + 3], s);
  }
  s += b_root[0];
  float m = s;
  #pragma unroll
  for (int o = 32; o > 0; o >>= 1) m = fmaxf(m, __shfl_xor(m, o, 64));
  float e = expf(s - m);
  float sum = e;
  #pragma unroll
  for (int o = 32; o > 0; o >>= 1) sum += __shfl_xor(sum, o, 64);
  outF[d * 64 + i] = e / sum;
}

// ---------------- attn: per doc, logits = P.C^T (MFMA), diag=NEG, softmax over i per column j ----------------
__global__ __launch_bounds__(256) void k_attn(const us* __restrict__ Pb, const us* __restrict__ Cb,
    float* __restrict__ Aout, us* __restrict__ Atb) {
  __shared__ float Ls[64][65];
  __shared__ float pm[4][64], psum[4][64];
  int d = blockIdx.x;
  int w = threadIdx.x >> 6, lane = threadIdx.x & 63;
  int lo = lane & 15, q = lane >> 4;
  const us* Pd = Pb + (long)d * 64 * 320;
  const us* Cd = Cb + (long)d * 64 * 320;
  f32x4 z = {0.f, 0.f, 0.f, 0.f};
  f32x4 acc[4]; acc[0] = z; acc[1] = z; acc[2] = z; acc[3] = z;
  const us* arow = Pd + (w * 16 + lo) * 320 + 8 * q;
  for (int ks = 0; ks < 10; ++ks) {
    bf16x8 av = ld8(arow + ks * 32);
    #pragma unroll
    for (int t2 = 0; t2 < 4; ++t2) {
      bf16x8 bv = ld8(Cd + (t2 * 16 + lo) * 320 + ks * 32 + 8 * q);
      acc[t2] = __builtin_amdgcn_mfma_f32_16x16x32_bf16(av, bv, acc[t2], 0, 0, 0);
    }
  }
  #pragma unroll
  for (int t2 = 0; t2 < 4; ++t2) {
    #pragma unroll
    for (int r = 0; r < 4; ++r) {
      int i = w * 16 + q * 4 + r, j = t2 * 16 + lo;
      Ls[i][j] = (i == j) ? NEG_INF : acc[t2][r];
    }
  }
  __syncthreads();
  int j = threadIdx.x & 63, p = threadIdx.x >> 6;
  float mx = -3.0e38f;
  for (int i = p * 16; i < p * 16 + 16; ++i) mx = fmaxf(mx, Ls[i][j]);
  pm[p][j] = mx;
  __syncthreads();
  float gmx = fmaxf(fmaxf(pm[0][j], pm[1][j]), fmaxf(pm[2][j], pm[3][j]));
  float s = 0.f;
  for (int i = p * 16; i < p * 16 + 16; ++i) s += expf(Ls[i][j] - gmx);
  psum[p][j] = s;
  __syncthreads();
  float inv = 1.f / (psum[0][j] + psum[1][j] + psum[2][j] + psum[3][j]);
  float* Ad = Aout + (long)d * 4096;
  us* Atd = Atb + (long)d * 4096;
  for (int i = p * 16; i < p * 16 + 16; ++i) {
    float a = expf(Ls[i][j] - gmx) * inv;
    Ad[i * 64 + j] = a;
    Atd[j * 64 + i] = f2b(a);
  }
}

// ---------------- glue: per doc, tmp = A^T.enc via MFMA, build u = [enc | tmp+fri*root | enc*rowsum] ----------------
__global__ __launch_bounds__(256) void k_glue(const float* __restrict__ Aout, const float* __restrict__ fri,
    const us* __restrict__ encb, const us* __restrict__ encTb, const us* __restrict__ Atb,
    const float* __restrict__ root, us* __restrict__ ub) {
  __shared__ float rs[64], frs[64];
  int d = blockIdx.x, t = threadIdx.x;
  const float* Ad = Aout + (long)d * 4096;
  if (t < 64) {
    float s = 0.f;
    for (int j2 = 0; j2 < 64; j2 += 4) {
      float4 v = *reinterpret_cast<const float4*>(Ad + t * 64 + j2);
      s += v.x + v.y + v.z + v.w;
    }
    rs[t] = s;
    frs[t] = fri[d * 64 + t];
  }
  __syncthreads();
  int w = t >> 6, lane = t & 63, lo = lane & 15, q = lane >> 4;
  const us* Atd = Atb + (long)d * 4096;
  bf16x8 av0 = ld8(Atd + (w * 16 + lo) * 64 + 8 * q);
  bf16x8 av1 = ld8(Atd + (w * 16 + lo) * 64 + 32 + 8 * q);
  for (int nt = 0; nt < 19; ++nt) {
    f32x4 acc = {0.f, 0.f, 0.f, 0.f};
    const us* brow = encTb + (long)(nt * 16 + lo) * 4096 + d * 64 + 8 * q;
    bf16x8 bv0 = ld8(brow);
    bf16x8 bv1 = ld8(brow + 32);
    acc = __builtin_amdgcn_mfma_f32_16x16x32_bf16(av0, bv0, acc, 0, 0, 0);
    acc = __builtin_amdgcn_mfma_f32_16x16x32_bf16(av1, bv1, acc, 0, 0, 0);
    int h = nt * 16 + lo;
    if (h < 300) {
      float rt = root[h];
      #pragma unroll
      for (int r = 0; r < 4; ++r) {
        int i = w * 16 + q * 4 + r;
        ub[(long)(d * 64 + i) * 928 + 300 + h] = f2b(acc[r] + frs[i] * rt);
      }
    }
  }
  for (int idx = t; idx < 64 * 300; idx += 256) {
    int r = idx / 300, c = idx - r * 300;
    us ev = encb[(long)(d * 64 + r) * 320 + c];
    ub[(long)(d * 64 + r) * 928 + c] = ev;
    ub[(long)(d * 64 + r) * 928 + 600 + c] = f2b(b2f(ev) * rs[r]);
  }
  for (int idx = t; idx < 64 * 28; idx += 256) {
    int r = idx / 28, c = 900 + (idx - r * 28);
    ub[(long)(d * 64 + r) * 928 + c] = 0;
  }
}

// ---------------- final: mean over i, tiny head ----------------
__global__ __launch_bounds__(256) void k_final(const float* __restrict__ ri,
    const float* __restrict__ W_cls, const float* __restrict__ b_cls,
    float* __restrict__ outp) {
  __shared__ float fin[300];
  __shared__ float red[256];
  int d = blockIdx.x, t = threadIdx.x;
  for (int h = t; h < 300; h += 256) {
    float s = 0.f;
    for (int i = 0; i < 64; ++i) s += ri[((d * 64) + i) * 300 + h];
    fin[h] = s * (1.0f / 64.0f);
  }
  __syncthreads();
  for (int c2 = 0; c2 < 2; ++c2) {
    float pth = 0.f;
    for (int h = t; h < 300; h += 256) pth = fmaf(fin[h], W_cls[c2 * 300 + h], pth);
    red[t] = pth;
    __syncthreads();
    for (int o = 128; o > 0; o >>= 1) {
      if (t < o) red[t] += red[t + o];
      __syncthreads();
    }
    if (t == 0) outp[d * 2 + c2] = red[0] + b_cls[c2];
    __syncthreads();
  }
}

extern "C" void kernel_launch(void* const* d_in, const int* in_sizes, int n_in,
                              void* d_out, int out_size, void* d_ws, size_t ws_size,
                              hipStream_t stream) {
  const int*   wi     = (const int*)d_in[0];
  const float* E      = (const float*)d_in[1];
  const float* W_sent = (const float*)d_in[2];
  const float* b_sent = (const float*)d_in[3];
  const float* W_par  = (const float*)d_in[4];
  const float* b_par  = (const float*)d_in[5];
  const float* W_ch   = (const float*)d_in[6];
  const float* b_ch   = (const float*)d_in[7];
  const float* w_root = (const float*)d_in[8];
  const float* b_root = (const float*)d_in[9];
  const float* root_e = (const float*)d_in[10];
  const float* W_r    = (const float*)d_in[11];
  const float* b_r    = (const float*)d_in[12];
  const float* W_cls  = (const float*)d_in[13];
  const float* b_cls  = (const float*)d_in[14];

  us* B = (us*)d_ws;
  us* Wsb  = B;                  //  97,280  [304][320]
  us* Wpb  = B + 97280;          //  97,280
  us* Wcb  = B + 194560;         //  97,280
  us* Wrb  = B + 291840;         // 282,112  [304][928]
  us* R    = B + 573952;         // region, 3,932,160 us
  us* xg   = R;                  // [4096][320]   (dead after enc gemm)
  us* Pb   = R + 1310720;        // [4096][320]   (dead after attn)
  us* Cb   = R + 2621440;        // [4096][320]   (dead after attn)
  us* ub   = R;                  // [4096][928]  aliases xg/Pb/Cb (written in k_glue)
  us* encb = B + 4506112;        // [4096][320]  (dead after glue)
  us* encTb= B + 5816832;        // [304][4096]  (dead after glue)
  us* Atb  = B + 7062016;        // [64][64][64] bf16 A^T per doc (dead after glue)
  float* p0 = (float*)(B + 4506112);  // [4096][300] fp32 ri partial 0 (overlays encb+encTb, post-glue)
  float* ri = (float*)(B + 7324160);  // [4096][300] fp32 (partial 1, finished in place)

  float* outp = (float*)d_out;      // [out(128) | A(262144) | fri(4096)]
  float* outA = outp + 128;
  float* outF = outp + 128 + 262144;

  k_prep<<<dim3(640, 6), 256, 0, stream>>>(wi, E, W_sent, W_par, W_ch, W_r,
                                           Wsb, Wpb, Wcb, Wrb, xg, encb, Pb, Cb);
  // enc = lrelu(xg . Wsent^T + b), also emit enc^T
  k_gemm_b<<<dim3(256, 1), 256, 0, stream>>>(xg, Wsb, b_sent, encb,
                                             (us*)nullptr, (float*)nullptr, (us*)nullptr, encTb);
  k_fri<<<64, 64, 0, stream>>>(encb, w_root, b_root, outF);
  // P and C in one launch
  k_gemm_b<<<dim3(256, 2), 256, 0, stream>>>(encb, Wpb, b_par, Pb,
                                             Wcb, b_ch, Cb, (us*)nullptr);
  k_attn<<<64, 256, 0, stream>>>(Pb, Cb, outA, Atb);
  k_glue<<<64, 256, 0, stream>>>(outA, outF, encb, encTb, Atb, root_e, ub);
  // ri partials (K split 15/14), then finish
  k_gemm_ri<<<dim3(256, 2), 256, 0, stream>>>(ub, Wrb, p0, ri);
  k_finish<<<2048, 256, 0, stream>>>(p0, ri, b_r, ri);
  k_final<<<64, 256, 0, stream>>>(ri, W_cls, b_cls, outp);
}